// Round 5
// baseline (246.848 us; speedup 1.0000x reference)
//
#include <hip/hip_runtime.h>

// QuantizedSpectralConv on MI355X (gfx950).
// x [8,32,256,256] f32; Tucker: core[16,16,16,9] F0[32,16] F1[32,16] F2[32,16]
// F3[17,9] complex, deq = q*scale+min. Active window: kx in [112,144),
// ky in [56,73) of the (256,129) rfft2. norm="forward" (1/65536 on fwd).
//
// Workspace (float2):
//   A1 [17 ky][256 bi][256 h]; X [544 mode][256 bi]; W4 [544][32][32];
//   Mx [544 mode][256 bo]
// LDS rule: addresses wave-uniform (broadcast) or lane-consecutive only.

__device__ __forceinline__ float2 cfma(float2 a, float2 b, float2 c) {
    c.x = fmaf(a.x, b.x, fmaf(-a.y, b.y, c.x));
    c.y = fmaf(a.x, b.y, fmaf(a.y, b.x, c.y));
    return c;
}
__device__ __forceinline__ float2 cmul(float2 a, float2 b) {
    return make_float2(a.x*b.x - a.y*b.y, a.x*b.y + a.y*b.x);
}

// ================= weights: dequant + full Tucker per mode =================
__global__ __launch_bounds__(256) void weights_kernel(
    const int* __restrict__ q_core, const int* __restrict__ q_f0,
    const int* __restrict__ q_f1, const int* __restrict__ q_f2,
    const int* __restrict__ q_f3,
    const float* __restrict__ core_scale, const float* __restrict__ core_min,
    const float* __restrict__ f_scales, const float* __restrict__ f_mins,
    float2* __restrict__ W4)
{
    __shared__ float2 F0s[512], F1s[512], skl[144];
    __shared__ float2 C2p[16*17];
    __shared__ float2 A2p[16*33];
    int t = threadIdx.x, m = blockIdx.x;
    int c = m / 17, d = m % 17;
    float cs = *core_scale, cm = *core_min;
    float s0 = f_scales[0], m0 = f_mins[0];
    float s1 = f_scales[1], m1 = f_mins[1];

    for (int e = t; e < 512; e += 256) {
        F0s[e] = make_float2(q_f0[2*e]*s0 + m0, q_f0[2*e+1]*s0 + m0);
        F1s[e] = make_float2(q_f1[2*e]*s1 + m1, q_f1[2*e+1]*s1 + m1);
    }
    if (t < 144) {
        int k = t / 9, l = t % 9;
        float s2 = f_scales[2], m2 = f_mins[2];
        float s3 = f_scales[3], m3 = f_mins[3];
        float2 f2 = make_float2(q_f2[2*(c*16+k)]*s2 + m2, q_f2[2*(c*16+k)+1]*s2 + m2);
        float2 f3 = make_float2(q_f3[2*(d*9+l)]*s3 + m3, q_f3[2*(d*9+l)+1]*s3 + m3);
        skl[t] = cmul(f2, f3);
    }
    __syncthreads();
    {   // phase 1: C2[i,j] = sum_{k,l} core[i,j,k,l]*F2[c,k]*F3[d,l]
        int i = t >> 4, j = t & 15;
        const int4* qc = (const int4*)(q_core + t * 288);
        float2 acc = make_float2(0.f, 0.f);
#pragma unroll 8
        for (int u = 0; u < 72; ++u) {
            int4 q = qc[u];
            float2 e0 = make_float2(q.x*cs + cm, q.y*cs + cm);
            float2 e1 = make_float2(q.z*cs + cm, q.w*cs + cm);
            acc = cfma(e0, skl[2*u], acc);
            acc = cfma(e1, skl[2*u+1], acc);
        }
        C2p[i*17 + j] = acc;
    }
    __syncthreads();
#pragma unroll
    for (int r = 0; r < 2; ++r) {   // phase 2: A2[i,b] = sum_j C2[i,j]*F1[b,j]
        int e = t + r*256; int i = e & 15, b = e >> 4;
        float2 acc = make_float2(0.f, 0.f);
#pragma unroll
        for (int j = 0; j < 16; ++j)
            acc = cfma(C2p[i*17 + j], F1s[b*16 + j], acc);
        A2p[i*33 + b] = acc;
    }
    __syncthreads();
    {   // phase 3: W4[m,a,b] = sum_i F0[a,i]*A2[i,b]
        int b = t & 31, a0 = t >> 5;
#pragma unroll
        for (int q = 0; q < 4; ++q) {
            int a = a0 + 8*q;
            float2 acc = make_float2(0.f, 0.f);
#pragma unroll
            for (int i = 0; i < 16; ++i)
                acc = cfma(F0s[a*16 + i], A2p[i*33 + b], acc);
            W4[m*1024 + a*32 + b] = acc;
        }
    }
}

// ================= forward partial DFT along w =================
template<int P>
__device__ __forceinline__ void quad_acc(float& ar, float& ai, float xv, float tx, float ty) {
    if (P == 0) { ar = fmaf(xv, tx, ar);  ai = fmaf(xv, ty, ai); }
    if (P == 1) { ar = fmaf(xv, ty, ar);  ai = fmaf(-xv, tx, ai); }   // *(-i)
    if (P == 2) { ar = fmaf(-xv, tx, ar); ai = fmaf(-xv, ty, ai); }   // *(-1)
    if (P == 3) { ar = fmaf(-xv, ty, ar); ai = fmaf(xv, tx, ai); }    // *(+i)
}

template<int KY0, int NKY>
__device__ __forceinline__ void fwdw_body(int lane, int row0, const float* xs,
                                          float2* __restrict__ A1)
{
    float ar[NKY], ai[NKY], tr[NKY], ti[NKY], sr[NKY], si[NKY];
#pragma unroll
    for (int j = 0; j < NKY; ++j) {
        ar[j] = 0.f; ai[j] = 0.f;
        const int kk = KY0 + j + 56;
        float a = kk * (1.f/128.f);
        sr[j] = cospif(a); si[j] = -sinpif(a);    // step e^{-2pi i kk/256}
        tr[j] = 1.f; ti[j] = 0.f;
    }
    for (int w = 0; w < 64; ++w) {
        float xv0 = xs[w*65 + lane];
        float xv1 = xs[(w+64)*65 + lane];
        float xv2 = xs[(w+128)*65 + lane];
        float xv3 = xs[(w+192)*65 + lane];
#pragma unroll
        for (int j = 0; j < NKY; ++j) {
            float tx = tr[j], ty = ti[j];
            const int pj = (KY0 + 56 + j) & 3;
            switch (pj) {
                case 0:
                    quad_acc<0>(ar[j], ai[j], xv0, tx, ty);
                    quad_acc<0>(ar[j], ai[j], xv1, tx, ty);
                    quad_acc<0>(ar[j], ai[j], xv2, tx, ty);
                    quad_acc<0>(ar[j], ai[j], xv3, tx, ty);
                    break;
                case 1:
                    quad_acc<0>(ar[j], ai[j], xv0, tx, ty);
                    quad_acc<1>(ar[j], ai[j], xv1, tx, ty);
                    quad_acc<2>(ar[j], ai[j], xv2, tx, ty);
                    quad_acc<3>(ar[j], ai[j], xv3, tx, ty);
                    break;
                case 2:
                    quad_acc<0>(ar[j], ai[j], xv0, tx, ty);
                    quad_acc<2>(ar[j], ai[j], xv1, tx, ty);
                    quad_acc<0>(ar[j], ai[j], xv2, tx, ty);
                    quad_acc<2>(ar[j], ai[j], xv3, tx, ty);
                    break;
                default:
                    quad_acc<0>(ar[j], ai[j], xv0, tx, ty);
                    quad_acc<3>(ar[j], ai[j], xv1, tx, ty);
                    quad_acc<2>(ar[j], ai[j], xv2, tx, ty);
                    quad_acc<1>(ar[j], ai[j], xv3, tx, ty);
                    break;
            }
            tr[j] = fmaf(tx, sr[j], -ty*si[j]);
            ti[j] = fmaf(tx, si[j],  ty*sr[j]);
        }
    }
    int row = row0 + lane;
#pragma unroll
    for (int j = 0; j < NKY; ++j)
        A1[(KY0 + j)*65536 + row] = make_float2(ar[j], ai[j]);
}

__global__ __launch_bounds__(256) void fwd_w_kernel(const float* __restrict__ x,
                                                    float2* __restrict__ A1)
{
    __shared__ float xs[256*65];        // [w][row] padded, conflict-free
    int tid = threadIdx.x;
    int row0 = blockIdx.x * 64;
    const float2* xf2 = (const float2*)x;
    for (int i2 = tid; i2 < 8192; i2 += 256) {
        int r = i2 >> 7, w2 = i2 & 127;
        float2 v = xf2[(size_t)(row0 + r)*128 + w2];
        xs[(2*w2)*65 + r]   = v.x;
        xs[(2*w2+1)*65 + r] = v.y;
    }
    __syncthreads();
    int lane = tid & 63, g = tid >> 6;
    if      (g == 0) fwdw_body<0, 5>(lane, row0, xs, A1);
    else if (g == 1) fwdw_body<5, 4>(lane, row0, xs, A1);
    else if (g == 2) fwdw_body<9, 4>(lane, row0, xs, A1);
    else             fwdw_body<13,4>(lane, row0, xs, A1);
}

// ================= forward partial DFT along h =================
__global__ __launch_bounds__(256) void fwd_h_kernel(const float2* __restrict__ A1,
                                                    float2* __restrict__ X)
{
    __shared__ float2 tbl[256];
    __shared__ float as_re[8*264];
    __shared__ float as_im[8*264];
    int tid = threadIdx.x;
    int ky = blockIdx.x >> 5, bi0 = (blockIdx.x & 31) * 8;
    tbl[tid] = make_float2(cospif(tid * (1.f/128.f)), -sinpif(tid * (1.f/128.f)));
    for (int idx = tid; idx < 2048; idx += 256) {
        int b = idx >> 8, h = idx & 255;
        float2 v = A1[ky*65536 + (bi0 + b)*256 + h];
        int ad = (h >> 5)*264 + (h & 31)*8 + b;
        as_re[ad] = v.x; as_im[ad] = v.y;
    }
    __syncthreads();
    int lane = tid & 63, g = tid >> 6;
    int bl = lane & 7, q = lane >> 3;
    int kx0 = g * 8;
    float2 acc[8];
#pragma unroll
    for (int j = 0; j < 8; ++j) acc[j] = make_float2(0.f, 0.f);
    int base = q*264 + bl;
    for (int hh = 0; hh < 32; ++hh) {
        float ar = as_re[base + hh*8];
        float ai = as_im[base + hh*8];
#pragma unroll
        for (int j = 0; j < 8; ++j) {
            int kk = kx0 + j + 112;
            float2 t = tbl[(kk * hh) & 255];      // wave-uniform broadcast
            acc[j].x = fmaf(ar, t.x, fmaf(-ai, t.y, acc[j].x));
            acc[j].y = fmaf(ar, t.y, fmaf( ai, t.x, acc[j].y));
        }
    }
#pragma unroll
    for (int j = 0; j < 8; ++j) {
        float a = (float)(j * q) * 0.25f;         // e^{-2pi i jq/8}
        float2 f = make_float2(cospif(a), -sinpif(a));
        float2 v = cmul(acc[j], f);
        v.x += __shfl_xor(v.x, 8);  v.y += __shfl_xor(v.y, 8);
        v.x += __shfl_xor(v.x, 16); v.y += __shfl_xor(v.y, 16);
        v.x += __shfl_xor(v.x, 32); v.y += __shfl_xor(v.y, 32);
        acc[j] = v;
    }
    if (q == 0) {
        const float inv = 1.f / 65536.f;
#pragma unroll
        for (int j = 0; j < 8; ++j)
            X[((kx0 + j)*17 + ky)*256 + bi0 + bl] =
                make_float2(acc[j].x * inv, acc[j].y * inv);
    }
}

// ================= per-mode channel mixing =================
__global__ __launch_bounds__(256) void mix_kernel(const float2* __restrict__ X,
                                                  const float2* __restrict__ W4,
                                                  float2* __restrict__ Mx)
{
    __shared__ float2 Xs[256];
    __shared__ float2 Ws[1024];
    int tid = threadIdx.x, mode = blockIdx.x;
    Xs[tid] = X[mode*256 + tid];
    for (int idx = tid; idx < 1024; idx += 256) Ws[idx] = W4[mode*1024 + idx];
    __syncthreads();
    int b = tid >> 5, o = tid & 31;
    float2 acc = make_float2(0.f, 0.f);
#pragma unroll
    for (int i = 0; i < 32; ++i)
        acc = cfma(Xs[b*32 + i], Ws[i*32 + o], acc);
    Mx[mode*256 + tid] = acc;
}

// ================= fused inverse — fully static codegen =================
// Grid 2048 = bo(256) x hc(8); block: 32 h-rows x 256 w.
// Phase 1: rotation recurrence (4 FMA/kx), no in-loop transcendentals.
// Phase 2: thread-per-w, C/NS in registers, static unrolled ky, float4 LDS reads.
__global__ __launch_bounds__(256) void inv_kernel(const float2* __restrict__ Mx,
                                                  const int* __restrict__ q_bias,
                                                  const float* __restrict__ b_scale,
                                                  const float* __restrict__ b_min,
                                                  float* __restrict__ out)
{
    __shared__ float2 ms[544];
    __shared__ __align__(16) float2 Ts[32*18];     // rows padded to 18 float2
    int tid = threadIdx.x;
    int bo = blockIdx.x & 255, hc = blockIdx.x >> 8;
    for (int idx = tid; idx < 544; idx += 256) ms[idx] = Mx[idx*256 + bo];
    __syncthreads();
    {   // ---- phase 1: Ts[hh][ky] = sum_kx ms[kx][ky] e^{+2pi i (kx+112)h/256}
        int hh = tid & 31, g = tid >> 5;           // g in [0,8): ky pair 2g (+3rd for g=7)
        int h = hc*32 + hh;
        float a0 = (float)((112 * h) & 255) * (1.f/128.f);
        float as = (float)(h & 255) * (1.f/128.f);
        float tr = cospif(a0), ti = sinpif(a0);    // e^{+2pi i 112h/256}
        float sr = cospif(as), si = sinpif(as);    // step e^{+2pi i h/256}
        int ky0 = 2*g;
        bool extra = (g == 7);
        float2 acc0 = make_float2(0.f, 0.f);
        float2 acc1 = make_float2(0.f, 0.f);
        float2 acc2 = make_float2(0.f, 0.f);
        const float2* mrow = ms + ky0;
        for (int kx = 0; kx < 32; ++kx) {
            float2 m0 = mrow[kx*17];
            float2 m1 = mrow[kx*17 + 1];
            acc0.x = fmaf(m0.x, tr, fmaf(-m0.y, ti, acc0.x));
            acc0.y = fmaf(m0.x, ti, fmaf( m0.y, tr, acc0.y));
            acc1.x = fmaf(m1.x, tr, fmaf(-m1.y, ti, acc1.x));
            acc1.y = fmaf(m1.x, ti, fmaf( m1.y, tr, acc1.y));
            if (extra) {
                float2 m2 = mrow[kx*17 + 2];
                acc2.x = fmaf(m2.x, tr, fmaf(-m2.y, ti, acc2.x));
                acc2.y = fmaf(m2.x, ti, fmaf( m2.y, tr, acc2.y));
            }
            float ntr = fmaf(tr, sr, -ti*si);      // t *= step
            ti = fmaf(tr, si, ti*sr);
            tr = ntr;
        }
        Ts[hh*18 + ky0]     = acc0;
        Ts[hh*18 + ky0 + 1] = acc1;
        if (extra) Ts[hh*18 + 16] = acc2;
    }
    __syncthreads();
    {   // ---- phase 2: out[h][w] = 2*(sum_ky Tx*C[ky] + Ty*NS[ky]) + bias
        int w = tid;
        float C[17], NS[17];
#pragma unroll
        for (int ky = 0; ky < 17; ++ky) {
            float a = (float)(((ky + 56) * w) & 255) * (1.f/128.f);
            C[ky]  = cospif(a);
            NS[ky] = -sinpif(a);
        }
        float bias = q_bias[bo & 31] * (*b_scale) + (*b_min);
        float* obase = out + (size_t)bo*65536 + (size_t)hc*32*256;
        for (int hh = 0; hh < 32; ++hh) {
            const float4* tp = (const float4*)(Ts + hh*18);
            float4 v0 = tp[0], v1 = tp[1], v2 = tp[2], v3 = tp[3];
            float4 v4 = tp[4], v5 = tp[5], v6 = tp[6], v7 = tp[7];
            float2 v8 = Ts[hh*18 + 16];
            float acc = 0.f;
            acc = fmaf(v0.x, C[0],  acc); acc = fmaf(v0.y, NS[0],  acc);
            acc = fmaf(v0.z, C[1],  acc); acc = fmaf(v0.w, NS[1],  acc);
            acc = fmaf(v1.x, C[2],  acc); acc = fmaf(v1.y, NS[2],  acc);
            acc = fmaf(v1.z, C[3],  acc); acc = fmaf(v1.w, NS[3],  acc);
            acc = fmaf(v2.x, C[4],  acc); acc = fmaf(v2.y, NS[4],  acc);
            acc = fmaf(v2.z, C[5],  acc); acc = fmaf(v2.w, NS[5],  acc);
            acc = fmaf(v3.x, C[6],  acc); acc = fmaf(v3.y, NS[6],  acc);
            acc = fmaf(v3.z, C[7],  acc); acc = fmaf(v3.w, NS[7],  acc);
            acc = fmaf(v4.x, C[8],  acc); acc = fmaf(v4.y, NS[8],  acc);
            acc = fmaf(v4.z, C[9],  acc); acc = fmaf(v4.w, NS[9],  acc);
            acc = fmaf(v5.x, C[10], acc); acc = fmaf(v5.y, NS[10], acc);
            acc = fmaf(v5.z, C[11], acc); acc = fmaf(v5.w, NS[11], acc);
            acc = fmaf(v6.x, C[12], acc); acc = fmaf(v6.y, NS[12], acc);
            acc = fmaf(v6.z, C[13], acc); acc = fmaf(v6.w, NS[13], acc);
            acc = fmaf(v7.x, C[14], acc); acc = fmaf(v7.y, NS[14], acc);
            acc = fmaf(v7.z, C[15], acc); acc = fmaf(v7.w, NS[15], acc);
            acc = fmaf(v8.x, C[16], acc); acc = fmaf(v8.y, NS[16], acc);
            obase[hh*256 + w] = fmaf(2.f, acc, bias);
        }
    }
}

extern "C" void kernel_launch(void* const* d_in, const int* in_sizes, int n_in,
                              void* d_out, int out_size, void* d_ws, size_t ws_size,
                              hipStream_t stream) {
    const float* x          = (const float*)d_in[0];
    const float* core_scale = (const float*)d_in[1];
    const float* core_min   = (const float*)d_in[2];
    const float* f_scales   = (const float*)d_in[3];
    const float* f_mins     = (const float*)d_in[4];
    const float* b_scale    = (const float*)d_in[5];
    const float* b_min      = (const float*)d_in[6];
    const int* q_core = (const int*)d_in[7];
    const int* q_f0   = (const int*)d_in[8];
    const int* q_f1   = (const int*)d_in[9];
    const int* q_f2   = (const int*)d_in[10];
    const int* q_f3   = (const int*)d_in[11];
    const int* q_bias = (const int*)d_in[12];
    float* out = (float*)d_out;

    float2* ws = (float2*)d_ws;
    float2* A1 = ws;                 // 1,114,112  [17][256 bi][256 h]
    float2* W4 = ws + 1114112;       //   557,056  [544][32][32]
    float2* X  = W4 + 557056;        //   139,264  [544][256]
    float2* Mx = X + 139264;         //   139,264  [544][256]
    (void)ws_size; (void)n_in; (void)in_sizes; (void)out_size;

    weights_kernel<<<544, 256, 0, stream>>>(q_core, q_f0, q_f1, q_f2, q_f3,
                                            core_scale, core_min, f_scales, f_mins, W4);
    fwd_w_kernel<<<1024, 256, 0, stream>>>(x, A1);
    fwd_h_kernel<<<544, 256, 0, stream>>>(A1, X);
    mix_kernel<<<544, 256, 0, stream>>>(X, W4, Mx);
    inv_kernel<<<2048, 256, 0, stream>>>(Mx, q_bias, b_scale, b_min, out);
}